// Round 3
// baseline (1496.878 us; speedup 1.0000x reference)
//
#include <hip/hip_runtime.h>
#include <math.h>

#define H 2048
#define T 8
#define NSTEP 24

__device__ __forceinline__ float sigmoidf_(float x) { return 1.0f / (1.0f + expf(-x)); }

// ws layout (floats):
// [0,H)        x        (current step input)
// [H,2H)       h0 buf A
// [2H,3H)      h0 buf B
// [3H,4H)      c0
// [4H,5H)      h1 buf A
// [5H,6H)      h1 buf B
// [6H,7H)      c1
// [7H]         xent accumulator

__global__ void init_state(const float* __restrict__ g_emb, float* __restrict__ ws) {
    int i = blockIdx.x * blockDim.x + threadIdx.x;
    if (i < H) {
        ws[i]         = g_emb[i];
        ws[H + i]     = 0.f;
        ws[2 * H + i] = 0.f;
        ws[3 * H + i] = 0.f;
        ws[4 * H + i] = 0.f;
        ws[5 * H + i] = 0.f;
        ws[6 * H + i] = 0.f;
    }
    if (i == 0) ws[7 * H] = 0.f;
}

// One 64-lane wave per output element j. The wave computes the 4 gate rows
// (i,f,g,o) = rows {j, H+j, 2H+j, 3H+j} of Wih@x + Whh@h, reduces, and lane 0
// applies the LSTM cell update. c is updated in place (only this wave touches
// c[j]); h output goes to a separate buffer (every wave reads all of hold).
__global__ __launch_bounds__(256) void lstm_cell(
    const float* __restrict__ Wih, const float* __restrict__ Whh,
    const float* __restrict__ xin, const float* __restrict__ hold,
    float* __restrict__ c, float* __restrict__ hnew) {
    const int lane = threadIdx.x & 63;
    const int j = blockIdx.x * 4 + (threadIdx.x >> 6);

    const float4* x4 = reinterpret_cast<const float4*>(xin);
    const float4* h4 = reinterpret_cast<const float4*>(hold);
    const float4* wi0 = reinterpret_cast<const float4*>(Wih + (size_t)(0 * H + j) * H);
    const float4* wi1 = reinterpret_cast<const float4*>(Wih + (size_t)(1 * H + j) * H);
    const float4* wi2 = reinterpret_cast<const float4*>(Wih + (size_t)(2 * H + j) * H);
    const float4* wi3 = reinterpret_cast<const float4*>(Wih + (size_t)(3 * H + j) * H);
    const float4* wh0 = reinterpret_cast<const float4*>(Whh + (size_t)(0 * H + j) * H);
    const float4* wh1 = reinterpret_cast<const float4*>(Whh + (size_t)(1 * H + j) * H);
    const float4* wh2 = reinterpret_cast<const float4*>(Whh + (size_t)(2 * H + j) * H);
    const float4* wh3 = reinterpret_cast<const float4*>(Whh + (size_t)(3 * H + j) * H);

    float a0 = 0.f, a1 = 0.f, a2 = 0.f, a3 = 0.f;
#pragma unroll
    for (int kk = lane; kk < H / 4; kk += 64) {
        float4 xv = x4[kk];
        float4 hv = h4[kk];
        float4 w;
        w = wi0[kk]; a0 += w.x * xv.x + w.y * xv.y + w.z * xv.z + w.w * xv.w;
        w = wh0[kk]; a0 += w.x * hv.x + w.y * hv.y + w.z * hv.z + w.w * hv.w;
        w = wi1[kk]; a1 += w.x * xv.x + w.y * xv.y + w.z * xv.z + w.w * xv.w;
        w = wh1[kk]; a1 += w.x * hv.x + w.y * hv.y + w.z * hv.z + w.w * hv.w;
        w = wi2[kk]; a2 += w.x * xv.x + w.y * xv.y + w.z * xv.z + w.w * xv.w;
        w = wh2[kk]; a2 += w.x * hv.x + w.y * hv.y + w.z * hv.z + w.w * hv.w;
        w = wi3[kk]; a3 += w.x * xv.x + w.y * xv.y + w.z * xv.z + w.w * xv.w;
        w = wh3[kk]; a3 += w.x * hv.x + w.y * hv.y + w.z * hv.z + w.w * hv.w;
    }

#pragma unroll
    for (int off = 32; off > 0; off >>= 1) {
        a0 += __shfl_down(a0, off, 64);
        a1 += __shfl_down(a1, off, 64);
        a2 += __shfl_down(a2, off, 64);
        a3 += __shfl_down(a3, off, 64);
    }

    if (lane == 0) {
        float cj = c[j];
        float c2 = sigmoidf_(a1) * cj + sigmoidf_(a0) * tanhf(a2);
        float h2 = sigmoidf_(a3) * tanhf(c2);
        c[j] = c2;
        hnew[j] = h2;
    }
}

// Single block: logits = h @ w_soft (2048x8), log-softmax, Gumbel-max argmax,
// write id (as float) + xent accumulation, copy chosen embedding into x.
__global__ __launch_bounds__(256) void sample_step(
    const float* __restrict__ hin, const float* __restrict__ Wsoft,
    const float* __restrict__ emb_l, const float* __restrict__ u_l,
    float* __restrict__ x, float* __restrict__ xent_sum,
    float* __restrict__ out, int step) {
    const int tid = threadIdx.x;
    const int lane = tid & 63;
    const int wv = tid >> 6;

    float acc[8];
#pragma unroll
    for (int t = 0; t < 8; ++t) acc[t] = 0.f;

    for (int j = tid; j < H; j += 256) {
        float hj = hin[j];
        const float4* wrow = reinterpret_cast<const float4*>(Wsoft + (size_t)j * T);
        float4 a = wrow[0];
        float4 b = wrow[1];
        acc[0] += hj * a.x; acc[1] += hj * a.y; acc[2] += hj * a.z; acc[3] += hj * a.w;
        acc[4] += hj * b.x; acc[5] += hj * b.y; acc[6] += hj * b.z; acc[7] += hj * b.w;
    }

#pragma unroll
    for (int t = 0; t < 8; ++t)
#pragma unroll
        for (int off = 32; off > 0; off >>= 1)
            acc[t] += __shfl_down(acc[t], off, 64);

    __shared__ float part[4][8];
    __shared__ int s_idx;
    if (lane == 0) {
#pragma unroll
        for (int t = 0; t < 8; ++t) part[wv][t] = acc[t];
    }
    __syncthreads();

    if (tid == 0) {
        float logits[8];
#pragma unroll
        for (int t = 0; t < 8; ++t)
            logits[t] = part[0][t] + part[1][t] + part[2][t] + part[3][t];
        float m = logits[0];
#pragma unroll
        for (int t = 1; t < 8; ++t) m = fmaxf(m, logits[t]);
        float se = 0.f;
#pragma unroll
        for (int t = 0; t < 8; ++t) se += expf(logits[t] - m);
        float lse = m + logf(se);
        int best = 0;
        float bestv = -3.0e38f;
#pragma unroll
        for (int t = 0; t < 8; ++t) {
            float lp = logits[t] - lse;
            float gb = -logf(-logf(u_l[t]));
            float v = lp + gb;
            if (v > bestv) { bestv = v; best = t; }
        }
        float xe = -(logits[best] - lse);
        float ns = *xent_sum + xe;
        *xent_sum = ns;
        out[step] = (float)best;
        if (step == NSTEP - 1) out[NSTEP] = ns / (float)NSTEP;
        s_idx = best;
    }
    __syncthreads();

    const float* e = emb_l + (size_t)s_idx * H;
    for (int j = tid; j < H; j += 256) x[j] = e[j];
}

extern "C" void kernel_launch(void* const* d_in, const int* in_sizes, int n_in,
                              void* d_out, int out_size, void* d_ws, size_t ws_size,
                              hipStream_t stream) {
    const float* g_emb  = (const float*)d_in[0];
    const float* w_emb  = (const float*)d_in[1];
    const float* w_soft = (const float*)d_in[2];
    const float* w_ih   = (const float*)d_in[3];
    const float* w_hh   = (const float*)d_in[4];
    const float* u      = (const float*)d_in[5];
    float* out = (float*)d_out;
    float* ws  = (float*)d_ws;

    float* x     = ws;
    float* h0[2] = {ws + H, ws + 2 * H};
    float* c0    = ws + 3 * H;
    float* h1[2] = {ws + 4 * H, ws + 5 * H};
    float* c1    = ws + 6 * H;
    float* xent  = ws + 7 * H;

    init_state<<<dim3(8), dim3(256), 0, stream>>>(g_emb, ws);

    const size_t LOFF = (size_t)4 * H * H;  // per-layer weight offset
    int p0 = 0, p1 = 0;
    for (int s = 0; s < NSTEP; ++s) {
        lstm_cell<<<dim3(H / 4), dim3(256), 0, stream>>>(
            w_ih, w_hh, x, h0[p0], c0, h0[p0 ^ 1]);
        p0 ^= 1;
        lstm_cell<<<dim3(H / 4), dim3(256), 0, stream>>>(
            w_ih + LOFF, w_hh + LOFF, h0[p0], h1[p1], c1, h1[p1 ^ 1]);
        p1 ^= 1;
        sample_step<<<dim3(1), dim3(256), 0, stream>>>(
            h1[p1], w_soft, w_emb + (size_t)s * T * H, u + (size_t)s * T,
            x, xent, out, s);
    }
}

// Round 4
// 1082.111 us; speedup vs baseline: 1.3833x; 1.3833x over previous
//
#include <hip/hip_runtime.h>
#include <hip/hip_fp16.h>
#include <math.h>

#define H 2048
#define T 8
#define NSTEP 24

__device__ __forceinline__ float sigmoidf_(float x) { return 1.0f / (1.0f + expf(-x)); }

// ws layout:
// floats [0,H)        x        (current step input)
// floats [H,2H)       h0 buf A
// floats [2H,3H)      h0 buf B
// floats [3H,4H)      c0
// floats [4H,5H)      h1 buf A
// floats [5H,6H)      h1 buf B
// floats [6H,7H)      c1
// float  [7H]         xent accumulator
// then (64KB-aligned): wih_h  = 2*4H*H halfs (67.1 MB)
//                      whh_h  = 2*4H*H halfs (67.1 MB)
// total ~134.3 MB of the 512 MiB ws.

__global__ void init_state(const float* __restrict__ g_emb, float* __restrict__ ws) {
    int i = blockIdx.x * blockDim.x + threadIdx.x;
    if (i < H) {
        ws[i]         = g_emb[i];
        ws[H + i]     = 0.f;
        ws[2 * H + i] = 0.f;
        ws[3 * H + i] = 0.f;
        ws[4 * H + i] = 0.f;
        ws[5 * H + i] = 0.f;
        ws[6 * H + i] = 0.f;
    }
    if (i == 0) ws[7 * H] = 0.f;
}

// fp32 -> fp16 weight conversion, 8 elements per thread-iter (32B in, 16B out).
__global__ __launch_bounds__(256) void f2h(const float* __restrict__ src,
                                           __half* __restrict__ dst, int n8) {
    int i = blockIdx.x * blockDim.x + threadIdx.x;
    const int stride = gridDim.x * blockDim.x;
    const float4* s4 = reinterpret_cast<const float4*>(src);
    float4* d4 = reinterpret_cast<float4*>(dst);
    for (; i < n8; i += stride) {
        float4 a = s4[2 * i];
        float4 b = s4[2 * i + 1];
        union { __half2 h[4]; float4 f; } o;
        o.h[0] = __floats2half2_rn(a.x, a.y);
        o.h[1] = __floats2half2_rn(a.z, a.w);
        o.h[2] = __floats2half2_rn(b.x, b.y);
        o.h[3] = __floats2half2_rn(b.z, b.w);
        d4[i] = o.f;
    }
}

// dot of 8 fp16 weights (packed in a float4) with 8 fp32 activations (2 float4s)
__device__ __forceinline__ float dot8(float4 w8, const float4 xa, const float4 xb) {
    const __half2* h = reinterpret_cast<const __half2*>(&w8);
    float2 f0 = __half22float2(h[0]);
    float2 f1 = __half22float2(h[1]);
    float2 f2 = __half22float2(h[2]);
    float2 f3 = __half22float2(h[3]);
    return f0.x * xa.x + f0.y * xa.y + f1.x * xa.z + f1.y * xa.w +
           f2.x * xb.x + f2.y * xb.y + f3.x * xb.z + f3.y * xb.w;
}

// One 64-lane wave per output element j; fp16 weights, fp32 state/accum.
__global__ __launch_bounds__(256) void lstm_cell_h(
    const __half* __restrict__ Wih, const __half* __restrict__ Whh,
    const float* __restrict__ xin, const float* __restrict__ hold,
    float* __restrict__ c, float* __restrict__ hnew) {
    const int lane = threadIdx.x & 63;
    const int j = blockIdx.x * 4 + (threadIdx.x >> 6);

    const float4* x4 = reinterpret_cast<const float4*>(xin);
    const float4* h4 = reinterpret_cast<const float4*>(hold);
    const float4* wi0 = reinterpret_cast<const float4*>(Wih + (size_t)(0 * H + j) * H);
    const float4* wi1 = reinterpret_cast<const float4*>(Wih + (size_t)(1 * H + j) * H);
    const float4* wi2 = reinterpret_cast<const float4*>(Wih + (size_t)(2 * H + j) * H);
    const float4* wi3 = reinterpret_cast<const float4*>(Wih + (size_t)(3 * H + j) * H);
    const float4* wh0 = reinterpret_cast<const float4*>(Whh + (size_t)(0 * H + j) * H);
    const float4* wh1 = reinterpret_cast<const float4*>(Whh + (size_t)(1 * H + j) * H);
    const float4* wh2 = reinterpret_cast<const float4*>(Whh + (size_t)(2 * H + j) * H);
    const float4* wh3 = reinterpret_cast<const float4*>(Whh + (size_t)(3 * H + j) * H);

    float a0 = 0.f, a1 = 0.f, a2 = 0.f, a3 = 0.f;
#pragma unroll
    for (int kk = lane; kk < H / 8; kk += 64) {  // 4 iterations
        float4 xa = x4[2 * kk], xb = x4[2 * kk + 1];
        float4 ha = h4[2 * kk], hb = h4[2 * kk + 1];
        a0 += dot8(wi0[kk], xa, xb) + dot8(wh0[kk], ha, hb);
        a1 += dot8(wi1[kk], xa, xb) + dot8(wh1[kk], ha, hb);
        a2 += dot8(wi2[kk], xa, xb) + dot8(wh2[kk], ha, hb);
        a3 += dot8(wi3[kk], xa, xb) + dot8(wh3[kk], ha, hb);
    }

#pragma unroll
    for (int off = 32; off > 0; off >>= 1) {
        a0 += __shfl_down(a0, off, 64);
        a1 += __shfl_down(a1, off, 64);
        a2 += __shfl_down(a2, off, 64);
        a3 += __shfl_down(a3, off, 64);
    }

    if (lane == 0) {
        float cj = c[j];
        float c2 = sigmoidf_(a1) * cj + sigmoidf_(a0) * tanhf(a2);
        float h2 = sigmoidf_(a3) * tanhf(c2);
        c[j] = c2;
        hnew[j] = h2;
    }
}

// Single block: logits = h @ w_soft (2048x8), log-softmax, Gumbel-max argmax,
// write id (as float) + xent accumulation, copy chosen embedding into x.
__global__ __launch_bounds__(256) void sample_step(
    const float* __restrict__ hin, const float* __restrict__ Wsoft,
    const float* __restrict__ emb_l, const float* __restrict__ u_l,
    float* __restrict__ x, float* __restrict__ xent_sum,
    float* __restrict__ out, int step) {
    const int tid = threadIdx.x;
    const int lane = tid & 63;
    const int wv = tid >> 6;

    float acc[8];
#pragma unroll
    for (int t = 0; t < 8; ++t) acc[t] = 0.f;

    for (int j = tid; j < H; j += 256) {
        float hj = hin[j];
        const float4* wrow = reinterpret_cast<const float4*>(Wsoft + (size_t)j * T);
        float4 a = wrow[0];
        float4 b = wrow[1];
        acc[0] += hj * a.x; acc[1] += hj * a.y; acc[2] += hj * a.z; acc[3] += hj * a.w;
        acc[4] += hj * b.x; acc[5] += hj * b.y; acc[6] += hj * b.z; acc[7] += hj * b.w;
    }

#pragma unroll
    for (int t = 0; t < 8; ++t)
#pragma unroll
        for (int off = 32; off > 0; off >>= 1)
            acc[t] += __shfl_down(acc[t], off, 64);

    __shared__ float part[4][8];
    __shared__ int s_idx;
    if (lane == 0) {
#pragma unroll
        for (int t = 0; t < 8; ++t) part[wv][t] = acc[t];
    }
    __syncthreads();

    if (tid == 0) {
        float logits[8];
#pragma unroll
        for (int t = 0; t < 8; ++t)
            logits[t] = part[0][t] + part[1][t] + part[2][t] + part[3][t];
        float m = logits[0];
#pragma unroll
        for (int t = 1; t < 8; ++t) m = fmaxf(m, logits[t]);
        float se = 0.f;
#pragma unroll
        for (int t = 0; t < 8; ++t) se += expf(logits[t] - m);
        float lse = m + logf(se);
        int best = 0;
        float bestv = -3.0e38f;
#pragma unroll
        for (int t = 0; t < 8; ++t) {
            float lp = logits[t] - lse;
            float gb = -logf(-logf(u_l[t]));
            float v = lp + gb;
            if (v > bestv) { bestv = v; best = t; }
        }
        float xe = -(logits[best] - lse);
        float ns = *xent_sum + xe;
        *xent_sum = ns;
        out[step] = (float)best;
        if (step == NSTEP - 1) out[NSTEP] = ns / (float)NSTEP;
        s_idx = best;
    }
    __syncthreads();

    const float* e = emb_l + (size_t)s_idx * H;
    for (int j = tid; j < H; j += 256) x[j] = e[j];
}

extern "C" void kernel_launch(void* const* d_in, const int* in_sizes, int n_in,
                              void* d_out, int out_size, void* d_ws, size_t ws_size,
                              hipStream_t stream) {
    const float* g_emb  = (const float*)d_in[0];
    const float* w_emb  = (const float*)d_in[1];
    const float* w_soft = (const float*)d_in[2];
    const float* w_ih   = (const float*)d_in[3];
    const float* w_hh   = (const float*)d_in[4];
    const float* u      = (const float*)d_in[5];
    float* out = (float*)d_out;
    float* ws  = (float*)d_ws;

    float* x     = ws;
    float* h0[2] = {ws + H, ws + 2 * H};
    float* c0    = ws + 3 * H;
    float* h1[2] = {ws + 4 * H, ws + 5 * H};
    float* c1    = ws + 6 * H;
    float* xent  = ws + 7 * H;

    const size_t NW = (size_t)2 * 4 * H * H;  // elements per weight tensor
    __half* wih_h = reinterpret_cast<__half*>((char*)d_ws + 65536);
    __half* whh_h = wih_h + NW;

    // one-time (per call) fp32 -> fp16 weight conversion into ws
    f2h<<<dim3(2048), dim3(256), 0, stream>>>(w_ih, wih_h, (int)(NW / 8));
    f2h<<<dim3(2048), dim3(256), 0, stream>>>(w_hh, whh_h, (int)(NW / 8));
    init_state<<<dim3(8), dim3(256), 0, stream>>>(g_emb, ws);

    const size_t LOFF = (size_t)4 * H * H;  // per-layer weight offset
    int p0 = 0, p1 = 0;
    for (int s = 0; s < NSTEP; ++s) {
        lstm_cell_h<<<dim3(H / 4), dim3(256), 0, stream>>>(
            wih_h, whh_h, x, h0[p0], c0, h0[p0 ^ 1]);
        p0 ^= 1;
        lstm_cell_h<<<dim3(H / 4), dim3(256), 0, stream>>>(
            wih_h + LOFF, whh_h + LOFF, h0[p0], h1[p1], c1, h1[p1 ^ 1]);
        p1 ^= 1;
        sample_step<<<dim3(1), dim3(256), 0, stream>>>(
            h1[p1], w_soft, w_emb + (size_t)s * T * H, u + (size_t)s * T,
            x, xent, out, s);
    }
}